// Round 7
// baseline (622.711 us; speedup 1.0000x reference)
//
#include <hip/hip_runtime.h>

typedef unsigned int u32;
typedef unsigned long long u64;

// ---------------- ws layout (u32 units) ----------------
#define WQ1  0      // uint4[32]  : {b|n<<16, Tpack_lo, Tpack_hi, 0}
#define WQ2  128    // [64][12]   : {b0,n0,b1,n1,b2,n2, T0,TL,TR, 0,0,0}
#define WQ3  896    // [128][16]  : {b00,n00,b01,n01,b10,n10,b11,n11,b20,n20,b21,n21, T0,TL,TR,0}
#define WQ4  2944   // [128][6][8]: per r {b0,b1,b2,b3, n0,n1,n2,n3}
#define WNA4 9088   // int[128]
#define WSC4 9216   // float[128]   (total 9344 u32 = 37376 B)

__device__ __forceinline__ int scanT(int na, float bb, float mm, float sc, float be, int lim) {
  for (int nm = 0; nm <= lim; ++nm) {
    float tt = (((float)(na - 2 * nm) + bb) - mm) * sc + be;
    if (tt < 0.0f) return nm;
  }
  return 1 << 20;  // never negative
}

__global__ void setup_pack(
    const float* __restrict__ w1, const float* __restrict__ w2,
    const float* __restrict__ w3, const float* __restrict__ w4,
    const float* __restrict__ b1, const float* __restrict__ g1, const float* __restrict__ be1,
    const float* __restrict__ m1, const float* __restrict__ v1,
    const float* __restrict__ b2, const float* __restrict__ g2, const float* __restrict__ be2,
    const float* __restrict__ m2, const float* __restrict__ v2,
    const float* __restrict__ b3, const float* __restrict__ g3, const float* __restrict__ be3,
    const float* __restrict__ m3, const float* __restrict__ v3,
    const float* __restrict__ g4, const float* __restrict__ v4,
    u32* __restrict__ ws) {
  const int t = threadIdx.x;
  if (t < 32) {                       // ---- L1 ----
    const int c = t;
    u32 wb = 0, wn = 0;
    for (int k = 0; k < 9; ++k) {
      float f = w1[c * 9 + k];
      if (f < 0.0f) wb |= 1u << k;
      if (f != 0.0f) wn |= 1u << k;
    }
    float sc = g1[c] / sqrtf(v1[c] + 1e-5f);
    u64 pack = 0;
    for (int v = 0; v <= 9; ++v) {
      u32 T = 15;
      for (int p = 0; p <= 9; ++p) {
        float tt = (((float)(v - 2 * p) + b1[c]) - m1[c]) * sc + be1[c];
        if (tt < 0.0f) { T = (u32)p; break; }
      }
      pack |= (u64)T << (4 * v);
    }
    u32* W = ws + WQ1 + c * 4;
    W[0] = wb | (wn << 16);
    W[1] = (u32)pack;
    W[2] = (u32)(pack >> 32);
    W[3] = 0;
  } else if (t < 96) {                // ---- L2 ----
    const int c = t - 32;
    u32 wb[3], wn[3];
    for (int k = 0; k < 3; ++k) {
      u32 b = 0, nn = 0;
      for (int ci = 0; ci < 32; ++ci) {
        float f = w2[(c * 32 + ci) * 3 + k];
        if (f < 0.0f) b |= 1u << ci;
        if (f != 0.0f) nn |= 1u << ci;
      }
      wb[k] = b; wn[k] = nn;
    }
    float sc = g2[c] / sqrtf(v2[c] + 1e-5f);
    int naI = __popc(wn[0]) + __popc(wn[1]) + __popc(wn[2]);
    int naL = __popc(wn[1]) + __popc(wn[2]);
    int naR = __popc(wn[0]) + __popc(wn[1]);
    int T0 = scanT(naI, b2[c], m2[c], sc, be2[c], 97);
    int TL = scanT(naL, b2[c], m2[c], sc, be2[c], 97) + __popc(wb[0] & wn[0]);
    int TR = scanT(naR, b2[c], m2[c], sc, be2[c], 97) + __popc(wb[2] & wn[2]);
    u32* W = ws + WQ2 + c * 12;
    W[0] = wb[0]; W[1] = wn[0]; W[2] = wb[1]; W[3] = wn[1]; W[4] = wb[2]; W[5] = wn[2];
    W[6] = (u32)T0; W[7] = (u32)TL; W[8] = (u32)TR; W[9] = 0; W[10] = 0; W[11] = 0;
  } else if (t < 224) {               // ---- L3 ----
    const int c = t - 96;
    u32 wb[3][2], wn[3][2];
    for (int k = 0; k < 3; ++k)
      for (int g = 0; g < 2; ++g) {
        u32 b = 0, nn = 0;
        for (int xx = 0; xx < 32; ++xx) {
          int ci = g * 32 + xx;
          float f = w3[(c * 64 + ci) * 3 + k];
          if (f < 0.0f) b |= 1u << xx;
          if (f != 0.0f) nn |= 1u << xx;
        }
        wb[k][g] = b; wn[k][g] = nn;
      }
    float sc = g3[c] / sqrtf(v3[c] + 1e-5f);
    int n0 = __popc(wn[0][0]) + __popc(wn[0][1]);
    int n1 = __popc(wn[1][0]) + __popc(wn[1][1]);
    int n2 = __popc(wn[2][0]) + __popc(wn[2][1]);
    int T0 = scanT(n0 + n1 + n2, b3[c], m3[c], sc, be3[c], 193);
    int TL = scanT(n1 + n2, b3[c], m3[c], sc, be3[c], 193)
             + __popc(wb[0][0] & wn[0][0]) + __popc(wb[0][1] & wn[0][1]);
    int TR = scanT(n0 + n1, b3[c], m3[c], sc, be3[c], 193)
             + __popc(wb[2][0] & wn[2][0]) + __popc(wb[2][1] & wn[2][1]);
    u32* W = ws + WQ3 + c * 16;
    for (int k = 0; k < 3; ++k)
      for (int g = 0; g < 2; ++g) { W[(k * 2 + g) * 2] = wb[k][g]; W[(k * 2 + g) * 2 + 1] = wn[k][g]; }
    W[12] = (u32)T0; W[13] = (u32)TL; W[14] = (u32)TR; W[15] = 0;
  } else if (t < 352) {               // ---- L4 ----
    const int c = t - 224;
    int na4 = 0;
    for (int r = 0; r < 6; ++r)
      for (int g = 0; g < 4; ++g) {
        u32 b = 0, nn = 0;
        for (int xx = 0; xx < 32; ++xx) {
          int ci = g * 32 + xx;
          float f = w4[(c * 128 + ci) * 6 + r];
          if (f < 0.0f) b |= 1u << xx;
          if (f != 0.0f) nn |= 1u << xx;
        }
        ws[WQ4 + c * 48 + r * 8 + g] = b;
        ws[WQ4 + c * 48 + r * 8 + 4 + g] = nn;
        na4 += __popc(nn);
      }
    ((int*)(ws + WNA4))[c] = na4;
    ((float*)(ws + WSC4))[c] = g4[c] / sqrtf(v4[c] + 1e-5f);
  }
}

// ---------------- fused network: one block (384 thr) per sample ----------------
__global__ __launch_bounds__(384) void bnn_fused(
    const float* __restrict__ x,
    const float* __restrict__ b4, const float* __restrict__ m4, const float* __restrict__ be4,
    const float* __restrict__ wfc, const float* __restrict__ bfc,
    const u32* __restrict__ ws, float* __restrict__ out) {
  __shared__ float h4[2048];
  __shared__ __align__(16) u32 s3b[6 * 16 * 4];
  __shared__ u32 s1b[6 * 34];
  __shared__ u32 s2b[6 * 34 * 2];
  __shared__ float red[40];

  const int t = threadIdx.x;
  const int n = blockIdx.x;
  const int lane = t & 63;
  const int wv = t >> 6;   // wave index 0..5

  // ---- Phase A: x signs via ballot; L1 conv+BN+htanh+pool as integer thresholds ----
  {
    const float* xp = x + n * 768 + wv * 128;   // wave = row
    float x0 = xp[lane], x1 = xp[lane + 64];
    u64 nb0 = __ballot(x0 < 0.0f);
    u64 nz0 = __ballot(x0 != 0.0f);
    u64 nb1 = __ballot(x1 < 0.0f);
    u64 nz1 = __ballot(x1 != 0.0f);
    // padded row bit-planes (4-bit pad | 128 | pad), uniform per wave
    u32 B0 = (u32)nb0 << 4, B1 = (u32)(nb0 >> 28), B2 = (u32)(nb0 >> 60) | ((u32)nb1 << 4);
    u32 B3 = (u32)(nb1 >> 28), B4 = (u32)(nb1 >> 60);
    u32 N0 = (u32)nz0 << 4, N1 = (u32)(nz0 >> 28), N2 = (u32)(nz0 >> 60) | ((u32)nz1 << 4);
    u32 N3 = (u32)(nz1 >> 28), N4 = (u32)(nz1 >> 60);
    // lane = conv position w (0..63); window = padded bits [2w, 2w+8]
    int s = lane * 2, k = s >> 5, sh = s & 31;
    bool k1 = (k & 1) != 0, k2 = (k & 2) != 0;
    u32 blo = k2 ? (k1 ? B3 : B2) : (k1 ? B1 : B0);
    u32 bhi = k2 ? (k1 ? B4 : B3) : (k1 ? B2 : B1);
    u32 nlo = k2 ? (k1 ? N3 : N2) : (k1 ? N1 : N0);
    u32 nhi = k2 ? (k1 ? N4 : N3) : (k1 ? N2 : N1);
    u32 xb = (u32)(((((u64)bhi << 32) | blo) >> sh)) & 0x1FF;
    u32 xn = (u32)(((((u64)nhi << 32) | nlo) >> sh)) & 0x1FF;
    const uint4* q1 = (const uint4*)(ws + WQ1);
    u32 word = 0;
#pragma unroll 8
    for (int c = 0; c < 32; ++c) {
      uint4 q = q1[c];
      u32 wb = q.x & 0x1FF, wn = q.x >> 16;
      u32 m = xn & wn;
      u32 v = (u32)__popc(m);
      int p1 = __popc((xb ^ wb) & m) + 1;
      u64 P = ((u64)q.z << 32) | q.y;
      int T = (int)((u32)(P >> (v << 2)) & 15u);
      word |= ((u32)(T - p1) >> 31) << c;
    }
    u32 pooled = word & __shfl_xor(word, 1, 64);
    if (!(lane & 1)) s1b[wv * 34 + 1 + (lane >> 1)] = pooled;
    if (lane == 1) s1b[wv * 34] = 0;
    if (lane == 3) s1b[wv * 34 + 33] = 0;
  }
  __syncthreads();

  // ---- Phase B: L2 conv(1x3,p1) sign bits; lane=position, loop=channel ----
  {
    int h = (t >= 192) ? 1 : 0;
    int hs = __builtin_amdgcn_readfirstlane(h);       // wave-uniform channel half
    int pp = t - 192 * h;
    int r = pp >> 5, w = pp & 31;
    if (t < 24) {                                     // zero s2 pad columns
      int rr = t >> 2, side = (t >> 1) & 1, g = t & 1;
      s2b[(rr * 34 + side * 33) * 2 + g] = 0;
    }
    u32 X0 = s1b[r * 34 + w], X1 = s1b[r * 34 + w + 1], X2 = s1b[r * 34 + w + 2];
    bool cL = (w == 0), cR = (w == 31);
    const u32* q2 = ws + WQ2 + hs * 32 * 12;
    u32 word = 0;
#pragma unroll 4
    for (int i = 0; i < 32; ++i) {
      const u32* W = q2 + i * 12;
      int nm1 = __popc((X0 ^ W[0]) & W[1]) + __popc((X1 ^ W[2]) & W[3])
              + __popc((X2 ^ W[4]) & W[5]) + 1;
      int T = cL ? (int)W[7] : (cR ? (int)W[8] : (int)W[6]);
      word |= ((u32)(T - nm1) >> 31) << i;
    }
    s2b[(r * 34 + w + 1) * 2 + h] = word;
  }
  __syncthreads();

  // ---- Phase C: L3 conv(1x3,p1)+pool sign bits ----
  {
    int h = (t >= 192) ? 1 : 0;
    int hs = __builtin_amdgcn_readfirstlane(h);
    int pp = t - 192 * h;
    int r = pp >> 5, w = pp & 31;
    const u32* S = s2b + (r * 34 + w) * 2;
    u32 X0 = S[0], X1 = S[1], X2 = S[2], X3 = S[3], X4 = S[4], X5 = S[5];
    bool cL = (w == 0), cR = (w == 31);
    const u32* q3 = ws + WQ3 + hs * 64 * 16;
    u32 w0 = 0, w1 = 0;
#pragma unroll 2
    for (int i = 0; i < 32; ++i) {
      {
        const u32* W = q3 + i * 16;
        int nm1 = __popc((X0 ^ W[0]) & W[1]) + __popc((X1 ^ W[2]) & W[3])
                + __popc((X2 ^ W[4]) & W[5]) + __popc((X3 ^ W[6]) & W[7])
                + __popc((X4 ^ W[8]) & W[9]) + __popc((X5 ^ W[10]) & W[11]) + 1;
        int T = cL ? (int)W[13] : (cR ? (int)W[14] : (int)W[12]);
        w0 |= ((u32)(T - nm1) >> 31) << i;
      }
      {
        const u32* W = q3 + (i + 32) * 16;
        int nm1 = __popc((X0 ^ W[0]) & W[1]) + __popc((X1 ^ W[2]) & W[3])
                + __popc((X2 ^ W[4]) & W[5]) + __popc((X3 ^ W[6]) & W[7])
                + __popc((X4 ^ W[8]) & W[9]) + __popc((X5 ^ W[10]) & W[11]) + 1;
        int T = cL ? (int)W[13] : (cR ? (int)W[14] : (int)W[12]);
        w1 |= ((u32)(T - nm1) >> 31) << i;
      }
    }
    u32 p0 = w0 & __shfl_xor(w0, 1, 64);
    u32 p1 = w1 & __shfl_xor(w1, 1, 64);
    if (!(pp & 1)) {
      int j = w >> 1;
      s3b[(r * 16 + j) * 4 + h * 2] = p0;
      s3b[(r * 16 + j) * 4 + h * 2 + 1] = p1;
    }
  }
  __syncthreads();

  // ---- Phase D: L4 conv(6x1 valid) + BN + htanh -> h4 floats ----
  {
    const int* na4 = (const int*)(ws + WNA4);
    const float* sc4 = (const float*)(ws + WSC4);
    for (int o = t; o < 2048; o += 384) {
      int c = o >> 4, w = o & 15;
      const uint4* Wb = (const uint4*)(ws + WQ4 + c * 48);
      const uint4* X = (const uint4*)(s3b) + w;
      int nm = 0;
#pragma unroll
      for (int r = 0; r < 6; ++r) {
        uint4 xv = X[r * 16];
        uint4 bv = Wb[r * 2], nv = Wb[r * 2 + 1];
        nm += __popc((xv.x ^ bv.x) & nv.x) + __popc((xv.y ^ bv.y) & nv.y)
            + __popc((xv.z ^ bv.z) & nv.z) + __popc((xv.w ^ bv.w) & nv.w);
      }
      float a = (float)(na4[c] - 2 * nm);
      float tt = ((a + b4[c]) - m4[c]) * sc4[c] + be4[c];
      h4[o] = fminf(1.0f, fmaxf(-1.0f, tt));
    }
  }
  __syncthreads();

  // ---- Phase E: FC (2048 -> 10), waves 0..3 ----
  if (t < 256) {
    float xv[8];
#pragma unroll
    for (int u = 0; u < 8; ++u) xv[u] = h4[t * 8 + u];
    float part[10];
#pragma unroll
    for (int o = 0; o < 10; ++o) {
      const float* wr = wfc + o * 2048 + t * 8;
      float sAcc = 0.0f;
#pragma unroll
      for (int u = 0; u < 8; ++u) sAcc += xv[u] * wr[u];
      part[o] = sAcc;
    }
#pragma unroll
    for (int o = 0; o < 10; ++o) {
      float v = part[o];
#pragma unroll
      for (int sft = 32; sft >= 1; sft >>= 1) v += __shfl_down(v, sft, 64);
      part[o] = v;
    }
    if (lane == 0) {
#pragma unroll
      for (int o = 0; o < 10; ++o) red[wv * 10 + o] = part[o];
    }
  }
  __syncthreads();
  if (t < 10) out[n * 10 + t] = red[t] + red[10 + t] + red[20 + t] + red[30 + t] + bfc[t];
}

extern "C" void kernel_launch(void* const* d_in, const int* in_sizes, int n_in,
                              void* d_out, int out_size, void* d_ws, size_t ws_size,
                              hipStream_t stream) {
  const float* x   = (const float*)d_in[0];
  const float* w1  = (const float*)d_in[1];
  const float* w2  = (const float*)d_in[2];
  const float* w3  = (const float*)d_in[3];
  const float* w4  = (const float*)d_in[4];
  const float* b1  = (const float*)d_in[5];
  const float* g1  = (const float*)d_in[6];
  const float* be1 = (const float*)d_in[7];
  const float* m1  = (const float*)d_in[8];
  const float* v1  = (const float*)d_in[9];
  const float* b2  = (const float*)d_in[10];
  const float* g2  = (const float*)d_in[11];
  const float* be2 = (const float*)d_in[12];
  const float* m2  = (const float*)d_in[13];
  const float* v2  = (const float*)d_in[14];
  const float* b3  = (const float*)d_in[15];
  const float* g3  = (const float*)d_in[16];
  const float* be3 = (const float*)d_in[17];
  const float* m3  = (const float*)d_in[18];
  const float* v3  = (const float*)d_in[19];
  const float* b4  = (const float*)d_in[20];
  const float* g4  = (const float*)d_in[21];
  const float* be4 = (const float*)d_in[22];
  const float* m4  = (const float*)d_in[23];
  const float* v4  = (const float*)d_in[24];
  const float* wfc = (const float*)d_in[25];
  const float* bfc = (const float*)d_in[26];
  u32* ws = (u32*)d_ws;
  float* out = (float*)d_out;

  const int N = in_sizes[0] / 768;   // 8192 samples

  setup_pack<<<1, 384, 0, stream>>>(w1, w2, w3, w4,
                                    b1, g1, be1, m1, v1,
                                    b2, g2, be2, m2, v2,
                                    b3, g3, be3, m3, v3,
                                    g4, v4, ws);
  bnn_fused<<<N, 384, 0, stream>>>(x, b4, m4, be4, wfc, bfc, ws, out);
}

// Round 8
// 555.683 us; speedup vs baseline: 1.1206x; 1.1206x over previous
//
#include <hip/hip_runtime.h>

typedef unsigned int u32;
typedef unsigned long long u64;

// ---------------- ws layout (u32 units) ----------------
#define WQ1  0      // uint4[32]  : {b|n<<16, Tpack_lo, Tpack_hi, 0}
#define WQ2  128    // [64][12]   : {b0,n0,b1,n1,b2,n2, T0,TL,TR, 0,0,0}
#define WQ3  896    // [128][16]  : {b00,n00,b01,n01,b10,n10,b11,n11,b20,n20,b21,n21, T0,TL,TR,0}
#define WQ4  2944   // [128][6][8]: per r {b0,b1,b2,b3, n0,n1,n2,n3}
#define WNA4 9088   // int[128]
#define WSC4 9216   // float[128]   (total 9344 u32 = 37376 B)

__device__ __forceinline__ int scanT(int na, float bb, float mm, float sc, float be, int lim) {
  for (int nm = 0; nm <= lim; ++nm) {
    float tt = (((float)(na - 2 * nm) + bb) - mm) * sc + be;
    if (tt < 0.0f) return nm;
  }
  return 1 << 20;  // never negative
}

__global__ void setup_pack(
    const float* __restrict__ w1, const float* __restrict__ w2,
    const float* __restrict__ w3, const float* __restrict__ w4,
    const float* __restrict__ b1, const float* __restrict__ g1, const float* __restrict__ be1,
    const float* __restrict__ m1, const float* __restrict__ v1,
    const float* __restrict__ b2, const float* __restrict__ g2, const float* __restrict__ be2,
    const float* __restrict__ m2, const float* __restrict__ v2,
    const float* __restrict__ b3, const float* __restrict__ g3, const float* __restrict__ be3,
    const float* __restrict__ m3, const float* __restrict__ v3,
    const float* __restrict__ g4, const float* __restrict__ v4,
    u32* __restrict__ ws) {
  const int t = threadIdx.x;
  if (t < 32) {                       // ---- L1 ----
    const int c = t;
    u32 wb = 0, wn = 0;
    for (int k = 0; k < 9; ++k) {
      float f = w1[c * 9 + k];
      if (f < 0.0f) wb |= 1u << k;
      if (f != 0.0f) wn |= 1u << k;
    }
    float sc = g1[c] / sqrtf(v1[c] + 1e-5f);
    u64 pack = 0;
    for (int v = 0; v <= 9; ++v) {
      u32 T = 15;
      for (int p = 0; p <= 9; ++p) {
        float tt = (((float)(v - 2 * p) + b1[c]) - m1[c]) * sc + be1[c];
        if (tt < 0.0f) { T = (u32)p; break; }
      }
      pack |= (u64)T << (4 * v);
    }
    u32* W = ws + WQ1 + c * 4;
    W[0] = wb | (wn << 16);
    W[1] = (u32)pack;
    W[2] = (u32)(pack >> 32);
    W[3] = 0;
  } else if (t < 96) {                // ---- L2 ----
    const int c = t - 32;
    u32 wb[3], wn[3];
    for (int k = 0; k < 3; ++k) {
      u32 b = 0, nn = 0;
      for (int ci = 0; ci < 32; ++ci) {
        float f = w2[(c * 32 + ci) * 3 + k];
        if (f < 0.0f) b |= 1u << ci;
        if (f != 0.0f) nn |= 1u << ci;
      }
      wb[k] = b; wn[k] = nn;
    }
    float sc = g2[c] / sqrtf(v2[c] + 1e-5f);
    int naI = __popc(wn[0]) + __popc(wn[1]) + __popc(wn[2]);
    int naL = __popc(wn[1]) + __popc(wn[2]);
    int naR = __popc(wn[0]) + __popc(wn[1]);
    int T0 = scanT(naI, b2[c], m2[c], sc, be2[c], 97);
    int TL = scanT(naL, b2[c], m2[c], sc, be2[c], 97) + __popc(wb[0] & wn[0]);
    int TR = scanT(naR, b2[c], m2[c], sc, be2[c], 97) + __popc(wb[2] & wn[2]);
    u32* W = ws + WQ2 + c * 12;
    W[0] = wb[0]; W[1] = wn[0]; W[2] = wb[1]; W[3] = wn[1]; W[4] = wb[2]; W[5] = wn[2];
    W[6] = (u32)T0; W[7] = (u32)TL; W[8] = (u32)TR; W[9] = 0; W[10] = 0; W[11] = 0;
  } else if (t < 224) {               // ---- L3 ----
    const int c = t - 96;
    u32 wb[3][2], wn[3][2];
    for (int k = 0; k < 3; ++k)
      for (int g = 0; g < 2; ++g) {
        u32 b = 0, nn = 0;
        for (int xx = 0; xx < 32; ++xx) {
          int ci = g * 32 + xx;
          float f = w3[(c * 64 + ci) * 3 + k];
          if (f < 0.0f) b |= 1u << xx;
          if (f != 0.0f) nn |= 1u << xx;
        }
        wb[k][g] = b; wn[k][g] = nn;
      }
    float sc = g3[c] / sqrtf(v3[c] + 1e-5f);
    int n0 = __popc(wn[0][0]) + __popc(wn[0][1]);
    int n1 = __popc(wn[1][0]) + __popc(wn[1][1]);
    int n2 = __popc(wn[2][0]) + __popc(wn[2][1]);
    int T0 = scanT(n0 + n1 + n2, b3[c], m3[c], sc, be3[c], 193);
    int TL = scanT(n1 + n2, b3[c], m3[c], sc, be3[c], 193)
             + __popc(wb[0][0] & wn[0][0]) + __popc(wb[0][1] & wn[0][1]);
    int TR = scanT(n0 + n1, b3[c], m3[c], sc, be3[c], 193)
             + __popc(wb[2][0] & wn[2][0]) + __popc(wb[2][1] & wn[2][1]);
    u32* W = ws + WQ3 + c * 16;
    for (int k = 0; k < 3; ++k)
      for (int g = 0; g < 2; ++g) { W[(k * 2 + g) * 2] = wb[k][g]; W[(k * 2 + g) * 2 + 1] = wn[k][g]; }
    W[12] = (u32)T0; W[13] = (u32)TL; W[14] = (u32)TR; W[15] = 0;
  } else if (t < 352) {               // ---- L4 ----
    const int c = t - 224;
    int na4 = 0;
    for (int r = 0; r < 6; ++r)
      for (int g = 0; g < 4; ++g) {
        u32 b = 0, nn = 0;
        for (int xx = 0; xx < 32; ++xx) {
          int ci = g * 32 + xx;
          float f = w4[(c * 128 + ci) * 6 + r];
          if (f < 0.0f) b |= 1u << xx;
          if (f != 0.0f) nn |= 1u << xx;
        }
        ws[WQ4 + c * 48 + r * 8 + g] = b;
        ws[WQ4 + c * 48 + r * 8 + 4 + g] = nn;
        na4 += __popc(nn);
      }
    ((int*)(ws + WNA4))[c] = na4;
    ((float*)(ws + WSC4))[c] = g4[c] / sqrtf(v4[c] + 1e-5f);
  }
}

// build padded 9-bit windows from ballot planes (shared k1,k2,sh in scope)
#define MKWIN(nb0, nz0, nb1, nz1, XB, XN)                                          \
  {                                                                                \
    u32 B0 = (u32)(nb0) << 4, B1 = (u32)((nb0) >> 28),                             \
        B2 = (u32)((nb0) >> 60) | ((u32)(nb1) << 4);                               \
    u32 B3 = (u32)((nb1) >> 28), B4 = (u32)((nb1) >> 60);                          \
    u32 N0 = (u32)(nz0) << 4, N1 = (u32)((nz0) >> 28),                             \
        N2 = (u32)((nz0) >> 60) | ((u32)(nz1) << 4);                               \
    u32 N3 = (u32)((nz1) >> 28), N4 = (u32)((nz1) >> 60);                          \
    u32 blo = k2 ? (k1 ? B3 : B2) : (k1 ? B1 : B0);                                \
    u32 bhi = k2 ? (k1 ? B4 : B3) : (k1 ? B2 : B1);                                \
    u32 nlo = k2 ? (k1 ? N3 : N2) : (k1 ? N1 : N0);                                \
    u32 nhi = k2 ? (k1 ? N4 : N3) : (k1 ? N2 : N1);                                \
    XB = (u32)(((((u64)bhi << 32) | blo) >> sh)) & 0x1FF;                          \
    XN = (u32)(((((u64)nhi << 32) | nlo) >> sh)) & 0x1FF;                          \
  }

// ---------------- fused network: one block (384 thr) per 2 samples ----------------
__global__ __launch_bounds__(384) void bnn_fused(
    const float* __restrict__ x,
    const float* __restrict__ b4, const float* __restrict__ m4, const float* __restrict__ be4,
    const float* __restrict__ wfc, const float* __restrict__ bfc,
    const u32* __restrict__ ws, float* __restrict__ out) {
  __shared__ float h4[2][2048];
  __shared__ __align__(16) u32 s3b[2][6 * 16 * 4];
  __shared__ u32 s1b[2][6 * 34];
  __shared__ u32 s2b[2][6 * 34 * 2];
  __shared__ float red[2][40];

  const int t = threadIdx.x;
  const int n = blockIdx.x;          // sample pair index
  const int lane = t & 63;
  const int wv = t >> 6;   // wave index 0..5 = input row

  // ---- Phase A: L1 conv+pool, both samples interleaved ----
  {
    const float* xpA = x + (2 * n + 0) * 768 + wv * 128;
    const float* xpB = x + (2 * n + 1) * 768 + wv * 128;
    float a0 = xpA[lane], a1 = xpA[lane + 64];
    float c0 = xpB[lane], c1 = xpB[lane + 64];
    u64 nbA0 = __ballot(a0 < 0.0f), nzA0 = __ballot(a0 != 0.0f);
    u64 nbA1 = __ballot(a1 < 0.0f), nzA1 = __ballot(a1 != 0.0f);
    u64 nbB0 = __ballot(c0 < 0.0f), nzB0 = __ballot(c0 != 0.0f);
    u64 nbB1 = __ballot(c1 < 0.0f), nzB1 = __ballot(c1 != 0.0f);
    int s = lane * 2, k = s >> 5, sh = s & 31;
    bool k1 = (k & 1) != 0, k2 = (k & 2) != 0;
    u32 xbA, xnA, xbB, xnB;
    MKWIN(nbA0, nzA0, nbA1, nzA1, xbA, xnA);
    MKWIN(nbB0, nzB0, nbB1, nzB1, xbB, xnB);
    const uint4* q1 = (const uint4*)(ws + WQ1);
    u32 wordA = 0, wordB = 0;
#pragma unroll 8
    for (int c = 0; c < 32; ++c) {
      uint4 q = q1[c];
      u32 wb = q.x & 0x1FF, wn = q.x >> 16;
      u64 P = ((u64)q.z << 32) | q.y;
      u32 mA = xnA & wn;
      int pA = __popc((xbA ^ wb) & mA) + 1;
      int TA = (int)((u32)(P >> ((u32)__popc(mA) << 2)) & 15u);
      wordA |= ((u32)(TA - pA) >> 31) << c;
      u32 mB = xnB & wn;
      int pB = __popc((xbB ^ wb) & mB) + 1;
      int TB = (int)((u32)(P >> ((u32)__popc(mB) << 2)) & 15u);
      wordB |= ((u32)(TB - pB) >> 31) << c;
    }
    u32 pooledA = wordA & __shfl_xor(wordA, 1, 64);
    u32 pooledB = wordB & __shfl_xor(wordB, 1, 64);
    if (!(lane & 1)) {
      s1b[0][wv * 34 + 1 + (lane >> 1)] = pooledA;
      s1b[1][wv * 34 + 1 + (lane >> 1)] = pooledB;
    }
    if (lane == 1) { s1b[0][wv * 34] = 0; s1b[1][wv * 34] = 0; }
    if (lane == 3) { s1b[0][wv * 34 + 33] = 0; s1b[1][wv * 34 + 33] = 0; }
  }
  __syncthreads();

  // ---- Phase B: L2 conv(1x3,p1) sign bits, both samples ----
  {
    int h = (t >= 192) ? 1 : 0;
    int hs = __builtin_amdgcn_readfirstlane(h);       // wave-uniform channel half
    int pp = t - 192 * h;
    int r = pp >> 5, w = pp & 31;
    if (t < 24) {                                     // zero s2 pad columns (both samples)
      int rr = t >> 2, side = (t >> 1) & 1, g = t & 1;
      s2b[0][(rr * 34 + side * 33) * 2 + g] = 0;
      s2b[1][(rr * 34 + side * 33) * 2 + g] = 0;
    }
    u32 XA0 = s1b[0][r * 34 + w], XA1 = s1b[0][r * 34 + w + 1], XA2 = s1b[0][r * 34 + w + 2];
    u32 XB0 = s1b[1][r * 34 + w], XB1 = s1b[1][r * 34 + w + 1], XB2 = s1b[1][r * 34 + w + 2];
    bool cL = (w == 0), cR = (w == 31);
    const u32* q2 = ws + WQ2 + hs * 32 * 12;
    u32 wordA = 0, wordB = 0;
#pragma unroll 4
    for (int i = 0; i < 32; ++i) {
      const u32* W = q2 + i * 12;
      int T = cL ? (int)W[7] : (cR ? (int)W[8] : (int)W[6]);
      int nmA = __popc((XA0 ^ W[0]) & W[1]) + __popc((XA1 ^ W[2]) & W[3])
              + __popc((XA2 ^ W[4]) & W[5]) + 1;
      wordA |= ((u32)(T - nmA) >> 31) << i;
      int nmB = __popc((XB0 ^ W[0]) & W[1]) + __popc((XB1 ^ W[2]) & W[3])
              + __popc((XB2 ^ W[4]) & W[5]) + 1;
      wordB |= ((u32)(T - nmB) >> 31) << i;
    }
    s2b[0][(r * 34 + w + 1) * 2 + h] = wordA;
    s2b[1][(r * 34 + w + 1) * 2 + h] = wordB;
  }
  __syncthreads();

  // ---- Phase C: L3 conv(1x3,p1)+pool sign bits, both samples ----
  {
    int h = (t >= 192) ? 1 : 0;
    int hs = __builtin_amdgcn_readfirstlane(h);
    int pp = t - 192 * h;
    int r = pp >> 5, w = pp & 31;
    const u32* SA = s2b[0] + (r * 34 + w) * 2;
    const u32* SB = s2b[1] + (r * 34 + w) * 2;
    u32 XA0 = SA[0], XA1 = SA[1], XA2 = SA[2], XA3 = SA[3], XA4 = SA[4], XA5 = SA[5];
    u32 XB0 = SB[0], XB1 = SB[1], XB2 = SB[2], XB3 = SB[3], XB4 = SB[4], XB5 = SB[5];
    bool cL = (w == 0), cR = (w == 31);
    const u32* q3 = ws + WQ3 + hs * 64 * 16;
    u32 w0A = 0, w1A = 0, w0B = 0, w1B = 0;
#pragma unroll 2
    for (int i = 0; i < 32; ++i) {
      {
        const u32* W = q3 + i * 16;
        int T = cL ? (int)W[13] : (cR ? (int)W[14] : (int)W[12]);
        int nmA = __popc((XA0 ^ W[0]) & W[1]) + __popc((XA1 ^ W[2]) & W[3])
                + __popc((XA2 ^ W[4]) & W[5]) + __popc((XA3 ^ W[6]) & W[7])
                + __popc((XA4 ^ W[8]) & W[9]) + __popc((XA5 ^ W[10]) & W[11]) + 1;
        w0A |= ((u32)(T - nmA) >> 31) << i;
        int nmB = __popc((XB0 ^ W[0]) & W[1]) + __popc((XB1 ^ W[2]) & W[3])
                + __popc((XB2 ^ W[4]) & W[5]) + __popc((XB3 ^ W[6]) & W[7])
                + __popc((XB4 ^ W[8]) & W[9]) + __popc((XB5 ^ W[10]) & W[11]) + 1;
        w0B |= ((u32)(T - nmB) >> 31) << i;
      }
      {
        const u32* W = q3 + (i + 32) * 16;
        int T = cL ? (int)W[13] : (cR ? (int)W[14] : (int)W[12]);
        int nmA = __popc((XA0 ^ W[0]) & W[1]) + __popc((XA1 ^ W[2]) & W[3])
                + __popc((XA2 ^ W[4]) & W[5]) + __popc((XA3 ^ W[6]) & W[7])
                + __popc((XA4 ^ W[8]) & W[9]) + __popc((XA5 ^ W[10]) & W[11]) + 1;
        w1A |= ((u32)(T - nmA) >> 31) << i;
        int nmB = __popc((XB0 ^ W[0]) & W[1]) + __popc((XB1 ^ W[2]) & W[3])
                + __popc((XB2 ^ W[4]) & W[5]) + __popc((XB3 ^ W[6]) & W[7])
                + __popc((XB4 ^ W[8]) & W[9]) + __popc((XB5 ^ W[10]) & W[11]) + 1;
        w1B |= ((u32)(T - nmB) >> 31) << i;
      }
    }
    u32 p0A = w0A & __shfl_xor(w0A, 1, 64);
    u32 p1A = w1A & __shfl_xor(w1A, 1, 64);
    u32 p0B = w0B & __shfl_xor(w0B, 1, 64);
    u32 p1B = w1B & __shfl_xor(w1B, 1, 64);
    if (!(pp & 1)) {
      int j = w >> 1;
      s3b[0][(r * 16 + j) * 4 + h * 2] = p0A;
      s3b[0][(r * 16 + j) * 4 + h * 2 + 1] = p1A;
      s3b[1][(r * 16 + j) * 4 + h * 2] = p0B;
      s3b[1][(r * 16 + j) * 4 + h * 2 + 1] = p1B;
    }
  }
  __syncthreads();

  // ---- Phase D: L4 conv(6x1 valid) + BN + htanh -> h4 floats, both samples ----
  {
    const int* na4 = (const int*)(ws + WNA4);
    const float* sc4 = (const float*)(ws + WSC4);
    for (int o = t; o < 2048; o += 384) {
      int c = o >> 4, w = o & 15;
      const uint4* Wb = (const uint4*)(ws + WQ4 + c * 48);
      const uint4* XA = (const uint4*)(s3b[0]) + w;
      const uint4* XB = (const uint4*)(s3b[1]) + w;
      int nmA = 0, nmB = 0;
#pragma unroll
      for (int r = 0; r < 6; ++r) {
        uint4 bv = Wb[r * 2], nv = Wb[r * 2 + 1];
        uint4 xa = XA[r * 16];
        nmA += __popc((xa.x ^ bv.x) & nv.x) + __popc((xa.y ^ bv.y) & nv.y)
             + __popc((xa.z ^ bv.z) & nv.z) + __popc((xa.w ^ bv.w) & nv.w);
        uint4 xb = XB[r * 16];
        nmB += __popc((xb.x ^ bv.x) & nv.x) + __popc((xb.y ^ bv.y) & nv.y)
             + __popc((xb.z ^ bv.z) & nv.z) + __popc((xb.w ^ bv.w) & nv.w);
      }
      float base = b4[c] - m4[c], sc = sc4[c], bee = be4[c];
      int na = na4[c];
      float ta = ((float)(na - 2 * nmA) + base) * sc + bee;
      float tb = ((float)(na - 2 * nmB) + base) * sc + bee;
      h4[0][o] = fminf(1.0f, fmaxf(-1.0f, ta));
      h4[1][o] = fminf(1.0f, fmaxf(-1.0f, tb));
    }
  }
  __syncthreads();

  // ---- Phase E: FC (2048 -> 10), waves 0..3, both samples ----
  if (t < 256) {
    float xa[8], xc[8];
#pragma unroll
    for (int u = 0; u < 8; ++u) { xa[u] = h4[0][t * 8 + u]; xc[u] = h4[1][t * 8 + u]; }
    float pa[10], pb[10];
#pragma unroll
    for (int o = 0; o < 10; ++o) {
      const float* wr = wfc + o * 2048 + t * 8;
      float sA = 0.0f, sB = 0.0f;
#pragma unroll
      for (int u = 0; u < 8; ++u) { sA += xa[u] * wr[u]; sB += xc[u] * wr[u]; }
      pa[o] = sA; pb[o] = sB;
    }
#pragma unroll
    for (int o = 0; o < 10; ++o) {
      float vA = pa[o], vB = pb[o];
#pragma unroll
      for (int sft = 32; sft >= 1; sft >>= 1) {
        vA += __shfl_down(vA, sft, 64);
        vB += __shfl_down(vB, sft, 64);
      }
      pa[o] = vA; pb[o] = vB;
    }
    if (lane == 0) {
#pragma unroll
      for (int o = 0; o < 10; ++o) { red[0][wv * 10 + o] = pa[o]; red[1][wv * 10 + o] = pb[o]; }
    }
  }
  __syncthreads();
  if (t < 10) {
    out[(2 * n + 0) * 10 + t] = red[0][t] + red[0][10 + t] + red[0][20 + t] + red[0][30 + t] + bfc[t];
    out[(2 * n + 1) * 10 + t] = red[1][t] + red[1][10 + t] + red[1][20 + t] + red[1][30 + t] + bfc[t];
  }
}

extern "C" void kernel_launch(void* const* d_in, const int* in_sizes, int n_in,
                              void* d_out, int out_size, void* d_ws, size_t ws_size,
                              hipStream_t stream) {
  const float* x   = (const float*)d_in[0];
  const float* w1  = (const float*)d_in[1];
  const float* w2  = (const float*)d_in[2];
  const float* w3  = (const float*)d_in[3];
  const float* w4  = (const float*)d_in[4];
  const float* b1  = (const float*)d_in[5];
  const float* g1  = (const float*)d_in[6];
  const float* be1 = (const float*)d_in[7];
  const float* m1  = (const float*)d_in[8];
  const float* v1  = (const float*)d_in[9];
  const float* b2  = (const float*)d_in[10];
  const float* g2  = (const float*)d_in[11];
  const float* be2 = (const float*)d_in[12];
  const float* m2  = (const float*)d_in[13];
  const float* v2  = (const float*)d_in[14];
  const float* b3  = (const float*)d_in[15];
  const float* g3  = (const float*)d_in[16];
  const float* be3 = (const float*)d_in[17];
  const float* m3  = (const float*)d_in[18];
  const float* v3  = (const float*)d_in[19];
  const float* b4  = (const float*)d_in[20];
  const float* g4  = (const float*)d_in[21];
  const float* be4 = (const float*)d_in[22];
  const float* m4  = (const float*)d_in[23];
  const float* v4  = (const float*)d_in[24];
  const float* wfc = (const float*)d_in[25];
  const float* bfc = (const float*)d_in[26];
  u32* ws = (u32*)d_ws;
  float* out = (float*)d_out;

  const int N = in_sizes[0] / 768;   // 8192 samples
  const int NP = N / 2;              // sample pairs per block

  setup_pack<<<1, 384, 0, stream>>>(w1, w2, w3, w4,
                                    b1, g1, be1, m1, v1,
                                    b2, g2, be2, m2, v2,
                                    b3, g3, be3, m3, v3,
                                    g4, v4, ws);
  bnn_fused<<<NP, 384, 0, stream>>>(x, b4, m4, be4, wfc, bfc, ws, out);
}

// Round 10
// 465.003 us; speedup vs baseline: 1.3392x; 1.1950x over previous
//
#include <hip/hip_runtime.h>

typedef unsigned int u32;
typedef unsigned long long u64;

// ---------------- ws layout (u32 units) ----------------
#define WQ1  0      // uint4[32]  : {b|n<<16, Tpack_lo, Tpack_hi, 0}
#define WQ2  128    // [64][12]   : {b0,n0,b1,n1,b2,n2, T0,TL,TR, 0,0,0}
#define WQ3  896    // [128][16]  : {b00,n00,b01,n01,b10,n10,b11,n11,b20,n20,b21,n21, T0,TL,TR,0}
#define WQ4  2944   // [128][6][8]: per r {b0,b1,b2,b3, n0,n1,n2,n3}
#define WNA4 9088   // int[128]
#define WSC4 9216   // float[128]   (total 9344 u32 = 37376 B)

__device__ __forceinline__ int scanT(int na, float bb, float mm, float sc, float be, int lim) {
  for (int nm = 0; nm <= lim; ++nm) {
    float tt = (((float)(na - 2 * nm) + bb) - mm) * sc + be;
    if (tt < 0.0f) return nm;
  }
  return 1 << 20;  // never negative
}

__global__ void setup_pack(
    const float* __restrict__ w1, const float* __restrict__ w2,
    const float* __restrict__ w3, const float* __restrict__ w4,
    const float* __restrict__ b1, const float* __restrict__ g1, const float* __restrict__ be1,
    const float* __restrict__ m1, const float* __restrict__ v1,
    const float* __restrict__ b2, const float* __restrict__ g2, const float* __restrict__ be2,
    const float* __restrict__ m2, const float* __restrict__ v2,
    const float* __restrict__ b3, const float* __restrict__ g3, const float* __restrict__ be3,
    const float* __restrict__ m3, const float* __restrict__ v3,
    const float* __restrict__ g4, const float* __restrict__ v4,
    u32* __restrict__ ws) {
  const int t = threadIdx.x;
  if (t < 32) {                       // ---- L1 ----
    const int c = t;
    u32 wb = 0, wn = 0;
    for (int k = 0; k < 9; ++k) {
      float f = w1[c * 9 + k];
      if (f < 0.0f) wb |= 1u << k;
      if (f != 0.0f) wn |= 1u << k;
    }
    float sc = g1[c] / sqrtf(v1[c] + 1e-5f);
    u64 pack = 0;
    for (int v = 0; v <= 9; ++v) {
      u32 T = 15;
      for (int p = 0; p <= 9; ++p) {
        float tt = (((float)(v - 2 * p) + b1[c]) - m1[c]) * sc + be1[c];
        if (tt < 0.0f) { T = (u32)p; break; }
      }
      pack |= (u64)T << (4 * v);
    }
    u32* W = ws + WQ1 + c * 4;
    W[0] = wb | (wn << 16);
    W[1] = (u32)pack;
    W[2] = (u32)(pack >> 32);
    W[3] = 0;
  } else if (t < 96) {                // ---- L2 ----
    const int c = t - 32;
    u32 wb[3], wn[3];
    for (int k = 0; k < 3; ++k) {
      u32 b = 0, nn = 0;
      for (int ci = 0; ci < 32; ++ci) {
        float f = w2[(c * 32 + ci) * 3 + k];
        if (f < 0.0f) b |= 1u << ci;
        if (f != 0.0f) nn |= 1u << ci;
      }
      wb[k] = b; wn[k] = nn;
    }
    float sc = g2[c] / sqrtf(v2[c] + 1e-5f);
    int naI = __popc(wn[0]) + __popc(wn[1]) + __popc(wn[2]);
    int naL = __popc(wn[1]) + __popc(wn[2]);
    int naR = __popc(wn[0]) + __popc(wn[1]);
    int T0 = scanT(naI, b2[c], m2[c], sc, be2[c], 97);
    int TL = scanT(naL, b2[c], m2[c], sc, be2[c], 97) + __popc(wb[0] & wn[0]);
    int TR = scanT(naR, b2[c], m2[c], sc, be2[c], 97) + __popc(wb[2] & wn[2]);
    u32* W = ws + WQ2 + c * 12;
    W[0] = wb[0]; W[1] = wn[0]; W[2] = wb[1]; W[3] = wn[1]; W[4] = wb[2]; W[5] = wn[2];
    W[6] = (u32)T0; W[7] = (u32)TL; W[8] = (u32)TR; W[9] = 0; W[10] = 0; W[11] = 0;
  } else if (t < 224) {               // ---- L3 ----
    const int c = t - 96;
    u32 wb[3][2], wn[3][2];
    for (int k = 0; k < 3; ++k)
      for (int g = 0; g < 2; ++g) {
        u32 b = 0, nn = 0;
        for (int xx = 0; xx < 32; ++xx) {
          int ci = g * 32 + xx;
          float f = w3[(c * 64 + ci) * 3 + k];
          if (f < 0.0f) b |= 1u << xx;
          if (f != 0.0f) nn |= 1u << xx;
        }
        wb[k][g] = b; wn[k][g] = nn;
      }
    float sc = g3[c] / sqrtf(v3[c] + 1e-5f);
    int n0 = __popc(wn[0][0]) + __popc(wn[0][1]);
    int n1 = __popc(wn[1][0]) + __popc(wn[1][1]);
    int n2 = __popc(wn[2][0]) + __popc(wn[2][1]);
    int T0 = scanT(n0 + n1 + n2, b3[c], m3[c], sc, be3[c], 193);
    int TL = scanT(n1 + n2, b3[c], m3[c], sc, be3[c], 193)
             + __popc(wb[0][0] & wn[0][0]) + __popc(wb[0][1] & wn[0][1]);
    int TR = scanT(n0 + n1, b3[c], m3[c], sc, be3[c], 193)
             + __popc(wb[2][0] & wn[2][0]) + __popc(wb[2][1] & wn[2][1]);
    u32* W = ws + WQ3 + c * 16;
    for (int k = 0; k < 3; ++k)
      for (int g = 0; g < 2; ++g) { W[(k * 2 + g) * 2] = wb[k][g]; W[(k * 2 + g) * 2 + 1] = wn[k][g]; }
    W[12] = (u32)T0; W[13] = (u32)TL; W[14] = (u32)TR; W[15] = 0;
  } else if (t < 352) {               // ---- L4 ----
    const int c = t - 224;
    int na4 = 0;
    for (int r = 0; r < 6; ++r)
      for (int g = 0; g < 4; ++g) {
        u32 b = 0, nn = 0;
        for (int xx = 0; xx < 32; ++xx) {
          int ci = g * 32 + xx;
          float f = w4[(c * 128 + ci) * 6 + r];
          if (f < 0.0f) b |= 1u << xx;
          if (f != 0.0f) nn |= 1u << xx;
        }
        ws[WQ4 + c * 48 + r * 8 + g] = b;
        ws[WQ4 + c * 48 + r * 8 + 4 + g] = nn;
        na4 += __popc(nn);
      }
    ((int*)(ws + WNA4))[c] = na4;
    ((float*)(ws + WSC4))[c] = g4[c] / sqrtf(v4[c] + 1e-5f);
  }
}

// build padded 9-bit windows from ballot planes (shared k1,k2,sh in scope)
#define MKWIN(nb0, nz0, nb1, nz1, XB, XN)                                          \
  {                                                                                \
    u32 B0 = (u32)(nb0) << 4, B1 = (u32)((nb0) >> 28),                             \
        B2 = (u32)((nb0) >> 60) | ((u32)(nb1) << 4);                               \
    u32 B3 = (u32)((nb1) >> 28), B4 = (u32)((nb1) >> 60);                          \
    u32 N0 = (u32)(nz0) << 4, N1 = (u32)((nz0) >> 28),                             \
        N2 = (u32)((nz0) >> 60) | ((u32)(nz1) << 4);                               \
    u32 N3 = (u32)((nz1) >> 28), N4 = (u32)((nz1) >> 60);                          \
    u32 blo = k2 ? (k1 ? B3 : B2) : (k1 ? B1 : B0);                                \
    u32 bhi = k2 ? (k1 ? B4 : B3) : (k1 ? B2 : B1);                                \
    u32 nlo = k2 ? (k1 ? N3 : N2) : (k1 ? N1 : N0);                                \
    u32 nhi = k2 ? (k1 ? N4 : N3) : (k1 ? N2 : N1);                                \
    XB = (u32)(((((u64)bhi << 32) | blo) >> sh)) & 0x1FF;                          \
    XN = (u32)(((((u64)nhi << 32) | nlo) >> sh)) & 0x1FF;                          \
  }

#define NS 4   // samples per block

// ---------------- fused network: one block (384 thr) per 4 samples ----------------
__global__ __launch_bounds__(384) void bnn_fused(
    const float* __restrict__ x,
    const float* __restrict__ b4, const float* __restrict__ m4, const float* __restrict__ be4,
    const float* __restrict__ wfc, const float* __restrict__ bfc,
    const u32* __restrict__ ws, float* __restrict__ out) {
  __shared__ u32 s1b[NS][6 * 34];
  __shared__ u32 s2b[NS][6 * 34 * 2];
  __shared__ __align__(16) u32 s3b[NS][6 * 16 * 4];
  __shared__ float red[NS][40];

  const int t = threadIdx.x;
  const int n = blockIdx.x;          // sample-quad index
  const int lane = t & 63;
  const int wv = t >> 6;   // wave index 0..5 = input row

  // ---- Phase A: L1 conv+pool, 4 samples interleaved ----
  {
    float x0[NS], x1[NS];
#pragma unroll
    for (int s = 0; s < NS; ++s) {
      const float* xp = x + (NS * n + s) * 768 + wv * 128;
      x0[s] = xp[lane]; x1[s] = xp[lane + 64];
    }
    int sp = lane * 2, kk = sp >> 5, sh = sp & 31;
    bool k1 = (kk & 1) != 0, k2 = (kk & 2) != 0;
    u32 xb[NS], xn[NS];
#pragma unroll
    for (int s = 0; s < NS; ++s) {
      u64 nb0 = __ballot(x0[s] < 0.0f), nz0 = __ballot(x0[s] != 0.0f);
      u64 nb1 = __ballot(x1[s] < 0.0f), nz1 = __ballot(x1[s] != 0.0f);
      MKWIN(nb0, nz0, nb1, nz1, xb[s], xn[s]);
    }
    const uint4* q1 = (const uint4*)(ws + WQ1);
    u32 word[NS] = {0, 0, 0, 0};
#pragma unroll 4
    for (int c = 0; c < 32; ++c) {
      uint4 q = q1[c];
      u32 wb = q.x & 0x1FF, wn = q.x >> 16;
      u64 P = ((u64)q.z << 32) | q.y;
#pragma unroll
      for (int s = 0; s < NS; ++s) {
        u32 m = xn[s] & wn;
        int p1 = __popc((xb[s] ^ wb) & m) + 1;
        int T = (int)((u32)(P >> ((u32)__popc(m) << 2)) & 15u);
        word[s] |= ((u32)(T - p1) >> 31) << c;
      }
    }
#pragma unroll
    for (int s = 0; s < NS; ++s) {
      u32 pooled = word[s] & __shfl_xor(word[s], 1, 64);
      if (!(lane & 1)) s1b[s][wv * 34 + 1 + (lane >> 1)] = pooled;
      if (lane == 1) s1b[s][wv * 34] = 0;
      if (lane == 3) s1b[s][wv * 34 + 33] = 0;
    }
  }
  __syncthreads();

  // ---- Phase B: L2 conv(1x3,p1) sign bits, 4 samples ----
  {
    int h = (t >= 192) ? 1 : 0;
    int hs = __builtin_amdgcn_readfirstlane(h);       // wave-uniform channel half
    int pp = t - 192 * h;
    int r = pp >> 5, w = pp & 31;
    if (t < 24 * NS) {                                // zero s2 pad columns
      int s = t / 24, i = t % 24;
      int rr = i >> 2, side = (i >> 1) & 1, g = i & 1;
      s2b[s][(rr * 34 + side * 33) * 2 + g] = 0;
    }
    u32 X0[NS], X1[NS], X2[NS];
#pragma unroll
    for (int s = 0; s < NS; ++s) {
      X0[s] = s1b[s][r * 34 + w];
      X1[s] = s1b[s][r * 34 + w + 1];
      X2[s] = s1b[s][r * 34 + w + 2];
    }
    bool cL = (w == 0), cR = (w == 31);
    const u32* q2 = ws + WQ2 + hs * 32 * 12;
    u32 word[NS] = {0, 0, 0, 0};
#pragma unroll 4
    for (int i = 0; i < 32; ++i) {
      const u32* W = q2 + i * 12;
      int T = cL ? (int)W[7] : (cR ? (int)W[8] : (int)W[6]);
#pragma unroll
      for (int s = 0; s < NS; ++s) {
        int nm1 = __popc((X0[s] ^ W[0]) & W[1]) + __popc((X1[s] ^ W[2]) & W[3])
                + __popc((X2[s] ^ W[4]) & W[5]) + 1;
        word[s] |= ((u32)(T - nm1) >> 31) << i;
      }
    }
#pragma unroll
    for (int s = 0; s < NS; ++s) s2b[s][(r * 34 + w + 1) * 2 + h] = word[s];
  }
  __syncthreads();

  // ---- Phase C: L3 conv(1x3,p1)+pool sign bits, 4 samples ----
  {
    int h = (t >= 192) ? 1 : 0;
    int hs = __builtin_amdgcn_readfirstlane(h);
    int pp = t - 192 * h;
    int r = pp >> 5, w = pp & 31;
    u32 X[NS][6];
#pragma unroll
    for (int s = 0; s < NS; ++s) {
      const u32* S = s2b[s] + (r * 34 + w) * 2;
#pragma unroll
      for (int q = 0; q < 6; ++q) X[s][q] = S[q];
    }
    bool cL = (w == 0), cR = (w == 31);
    const u32* q3 = ws + WQ3 + hs * 64 * 16;
    u32 w0[NS] = {0, 0, 0, 0}, w1[NS] = {0, 0, 0, 0};
#pragma unroll 2
    for (int i = 0; i < 32; ++i) {
      {
        const u32* W = q3 + i * 16;
        int T = cL ? (int)W[13] : (cR ? (int)W[14] : (int)W[12]);
#pragma unroll
        for (int s = 0; s < NS; ++s) {
          int nm1 = __popc((X[s][0] ^ W[0]) & W[1]) + __popc((X[s][1] ^ W[2]) & W[3])
                  + __popc((X[s][2] ^ W[4]) & W[5]) + __popc((X[s][3] ^ W[6]) & W[7])
                  + __popc((X[s][4] ^ W[8]) & W[9]) + __popc((X[s][5] ^ W[10]) & W[11]) + 1;
          w0[s] |= ((u32)(T - nm1) >> 31) << i;
        }
      }
      {
        const u32* W = q3 + (i + 32) * 16;
        int T = cL ? (int)W[13] : (cR ? (int)W[14] : (int)W[12]);
#pragma unroll
        for (int s = 0; s < NS; ++s) {
          int nm1 = __popc((X[s][0] ^ W[0]) & W[1]) + __popc((X[s][1] ^ W[2]) & W[3])
                  + __popc((X[s][2] ^ W[4]) & W[5]) + __popc((X[s][3] ^ W[6]) & W[7])
                  + __popc((X[s][4] ^ W[8]) & W[9]) + __popc((X[s][5] ^ W[10]) & W[11]) + 1;
          w1[s] |= ((u32)(T - nm1) >> 31) << i;
        }
      }
    }
#pragma unroll
    for (int s = 0; s < NS; ++s) {
      u32 p0 = w0[s] & __shfl_xor(w0[s], 1, 64);
      u32 p1 = w1[s] & __shfl_xor(w1[s], 1, 64);
      if (!(pp & 1)) {
        int j = w >> 1;
        s3b[s][(r * 16 + j) * 4 + h * 2] = p0;
        s3b[s][(r * 16 + j) * 4 + h * 2 + 1] = p1;
      }
    }
  }
  __syncthreads();

  // ---- Phase D+E fused: L4 conv + BN + htanh in regs, then FC, 4 samples ----
  // thread t<256 owns channel c=t>>1, w-range q8=(t&1)*8 .. +8  (flat h4 idx 8t..8t+8)
  if (t < 256) {
    const int c = t >> 1, q8 = (t & 1) * 8;
    int nm[NS][8];
#pragma unroll
    for (int s = 0; s < NS; ++s)
#pragma unroll
      for (int j = 0; j < 8; ++j) nm[s][j] = 0;
    const uint4* Wb = (const uint4*)(ws + WQ4 + c * 48);
#pragma unroll
    for (int r = 0; r < 6; ++r) {
      uint4 bv = Wb[r * 2], nv = Wb[r * 2 + 1];
#pragma unroll
      for (int j = 0; j < 8; ++j) {
#pragma unroll
        for (int s = 0; s < NS; ++s) {
          uint4 xv = *((const uint4*)(s3b[s]) + r * 16 + q8 + j);
          nm[s][j] += __popc((xv.x ^ bv.x) & nv.x) + __popc((xv.y ^ bv.y) & nv.y)
                    + __popc((xv.z ^ bv.z) & nv.z) + __popc((xv.w ^ bv.w) & nv.w);
        }
      }
    }
    const int nav = ((const int*)(ws + WNA4))[c];
    const float base = b4[c] - m4[c];
    const float scv = ((const float*)(ws + WSC4))[c];
    const float bev = be4[c];
    float hv[NS][8];
#pragma unroll
    for (int s = 0; s < NS; ++s)
#pragma unroll
      for (int j = 0; j < 8; ++j) {
        float tt = ((float)(nav - 2 * nm[s][j]) + base) * scv + bev;
        hv[s][j] = fminf(1.0f, fmaxf(-1.0f, tt));
      }
    // FC: immediate per-output reduce
#pragma unroll
    for (int o = 0; o < 10; ++o) {
      const float* wr = wfc + o * 2048 + t * 8;
      float wv8[8];
#pragma unroll
      for (int u = 0; u < 8; ++u) wv8[u] = wr[u];
      float acc[NS];
#pragma unroll
      for (int s = 0; s < NS; ++s) {
        float a = 0.0f;
#pragma unroll
        for (int u = 0; u < 8; ++u) a += hv[s][u] * wv8[u];
        acc[s] = a;
      }
#pragma unroll
      for (int sft = 32; sft >= 1; sft >>= 1) {
#pragma unroll
        for (int s = 0; s < NS; ++s) acc[s] += __shfl_down(acc[s], sft, 64);
      }
      if (lane == 0) {
#pragma unroll
        for (int s = 0; s < NS; ++s) red[s][wv * 10 + o] = acc[s];
      }
    }
  }
  __syncthreads();
  if (t < 10 * NS) {
    int s = t / 10, o = t - s * 10;
    out[(NS * n + s) * 10 + o] =
        red[s][o] + red[s][10 + o] + red[s][20 + o] + red[s][30 + o] + bfc[o];
  }
}

extern "C" void kernel_launch(void* const* d_in, const int* in_sizes, int n_in,
                              void* d_out, int out_size, void* d_ws, size_t ws_size,
                              hipStream_t stream) {
  const float* x   = (const float*)d_in[0];
  const float* w1  = (const float*)d_in[1];
  const float* w2  = (const float*)d_in[2];
  const float* w3  = (const float*)d_in[3];
  const float* w4  = (const float*)d_in[4];
  const float* b1  = (const float*)d_in[5];
  const float* g1  = (const float*)d_in[6];
  const float* be1 = (const float*)d_in[7];
  const float* m1  = (const float*)d_in[8];
  const float* v1  = (const float*)d_in[9];
  const float* b2  = (const float*)d_in[10];
  const float* g2  = (const float*)d_in[11];
  const float* be2 = (const float*)d_in[12];
  const float* m2  = (const float*)d_in[13];
  const float* v2  = (const float*)d_in[14];
  const float* b3  = (const float*)d_in[15];
  const float* g3  = (const float*)d_in[16];
  const float* be3 = (const float*)d_in[17];
  const float* m3  = (const float*)d_in[18];
  const float* v3  = (const float*)d_in[19];
  const float* b4  = (const float*)d_in[20];
  const float* g4  = (const float*)d_in[21];
  const float* be4 = (const float*)d_in[22];
  const float* m4  = (const float*)d_in[23];
  const float* v4  = (const float*)d_in[24];
  const float* wfc = (const float*)d_in[25];
  const float* bfc = (const float*)d_in[26];
  u32* ws = (u32*)d_ws;
  float* out = (float*)d_out;

  const int N = in_sizes[0] / 768;   // 8192 samples
  const int NQ = N / NS;             // sample quads per block

  setup_pack<<<1, 384, 0, stream>>>(w1, w2, w3, w4,
                                    b1, g1, be1, m1, v1,
                                    b2, g2, be2, m2, v2,
                                    b3, g3, be3, m3, v3,
                                    g4, v4, ws);
  bnn_fused<<<NQ, 384, 0, stream>>>(x, b4, m4, be4, wfc, bfc, ws, out);
}